// Round 9
// baseline (85.902 us; speedup 1.0000x reference)
//
#include <hip/hip_runtime.h>

#define NPTS 8192
#define NQ   2048
#define NBATCH 8
#define KNN  32
#define R2   0.04f   // fp32 cast of python 0.2**2
#define NQTOT (NBATCH * NQ)
#define PACK_F4 (NBATCH * NPTS)

// Pack pos (AoS, 12B stride) into float4(x,y,z,|p|^2). Norm with explicit
// round-to-nearest ops, no FMA contraction, reference order: (x*x+y*y)+z*z.
__global__ __launch_bounds__(256)
void gg_prep(const float* __restrict__ pos, float4* __restrict__ pack, int total) {
    int i = blockIdx.x * blockDim.x + threadIdx.x;
    if (i >= total) return;
    float x = pos[i * 3 + 0];
    float y = pos[i * 3 + 1];
    float z = pos[i * 3 + 2];
    float n = __fadd_rn(__fadd_rn(__fmul_rn(x, x), __fmul_rn(y, y)), __fmul_rn(z, z));
    pack[i] = make_float4(x, y, z, n);
}

// Branch-free test of 128 points [SUBI, SUBI+128) for one query: lane handles
// SUBI+lane and SUBI+64+lane. One col/first update per 128 pts. Distance
// matches reference op order exactly:
//   s = (cn + pn) - 2*((cx*px + cy*py) + cz*pz)
#define TEST128Q(C, COL, FIRST, OQ, PA, PB, SUBI)                                  \
    {                                                                              \
        float dotA = __fadd_rn(__fadd_rn(__fmul_rn((C).x, (PA).x),                 \
                                         __fmul_rn((C).y, (PA).y)),                \
                               __fmul_rn((C).z, (PA).z));                          \
        float sA   = __fsub_rn(__fadd_rn((C).w, (PA).w), __fmul_rn(2.0f, dotA));   \
        float dotB = __fadd_rn(__fadd_rn(__fmul_rn((C).x, (PB).x),                 \
                                         __fmul_rn((C).y, (PB).y)),                \
                               __fmul_rn((C).z, (PB).z));                          \
        float sB   = __fsub_rn(__fadd_rn((C).w, (PB).w), __fmul_rn(2.0f, dotB));   \
        bool kA = !(sA > R2), kB = !(sB > R2);                                     \
        unsigned long long mA = __ballot(kA), mB = __ballot(kB);                   \
        int pcA = (int)__popcll(mA);                                               \
        int pfA = (int)__builtin_amdgcn_mbcnt_hi((unsigned)(mA >> 32),             \
                      __builtin_amdgcn_mbcnt_lo((unsigned)mA, 0u));                \
        int pfB = (int)__builtin_amdgcn_mbcnt_hi((unsigned)(mB >> 32),             \
                      __builtin_amdgcn_mbcnt_lo((unsigned)mB, 0u));                \
        int slA = (COL) + pfA;                                                     \
        int slB = (COL) + pcA + pfB;                                               \
        if (kA && slA < KNN) (OQ)[slA] = (SUBI) + lane;                            \
        if (kB && slB < KNN) (OQ)[slB] = (SUBI) + 64 + lane;                       \
        (FIRST) = ((COL) == 0 && mA) ? (SUBI) + (int)__builtin_ctzll(mA) : (FIRST);\
        (FIRST) = ((COL) == 0 && !mA && mB)                                        \
                      ? (SUBI) + 64 + (int)__builtin_ctzll(mB) : (FIRST);          \
        (COL) += pcA + (int)__popcll(mB);                                          \
    }

// One wave per TWO adjacent queries. Depth-2 register double-buffer software
// pipeline: buffer u holds points [base,base+256), buffer v [base+256,base+512).
// Refill of a buffer is issued right after the TESTs that consume it (WAR safe),
// targeting +512 points ahead -> up to 8 loads in flight per wave, and the
// compiler need only drain the OLDER 4 loads (vmcnt(4)) before each TEST block,
// never vmcnt(0). 4 waves/block, 2048 blocks = 8192 waves (8/SIMD). No atomics.
__global__ __launch_bounds__(256)
void gg_ballquery(const float4* __restrict__ pack,
                  const int* __restrict__ centroids,
                  int* __restrict__ out) {
    const int wid  = threadIdx.x >> 6;
    const int lane = threadIdx.x & 63;
    const int w    = blockIdx.x * 4 + wid;          // wave id: 0 .. 8191
    const int q0   = w * 2;                         // two consecutive queries
    const int b    = q0 >> 11;                      // batch

    const float4* __restrict__ pp = pack + b * NPTS;

    const float4 cA = pp[centroids[q0]];
    const float4 cB = pp[centroids[q0 + 1]];

    int* __restrict__ oA = out + q0 * KNN;
    int* __restrict__ oB = oA + KNN;

    int colA = 0, colB = 0;
    int fA = NPTS, fB = NPTS;

    // Prime the pipeline: u = [0,256), v = [256,512)
    float4 u0 = pp[lane];
    float4 u1 = pp[lane + 64];
    float4 u2 = pp[lane + 128];
    float4 u3 = pp[lane + 192];
    float4 v0 = pp[lane + 256];
    float4 v1 = pp[lane + 320];
    float4 v2 = pp[lane + 384];
    float4 v3 = pp[lane + 448];

    #pragma unroll 1
    for (int base = 0; base < NPTS; base += 512) {
        // ---- chunk U: points [base, base+256)
        if (colA < KNN) {
            TEST128Q(cA, colA, fA, oA, u0, u1, base);
            TEST128Q(cA, colA, fA, oA, u2, u3, base + 128);
        }
        if (colB < KNN) {
            TEST128Q(cB, colB, fB, oB, u0, u1, base);
            TEST128Q(cB, colB, fB, oB, u2, u3, base + 128);
        }
        if (colA >= KNN && colB >= KNN) break;
        if (base + 512 < NPTS) {            // refill u for [base+512, base+768)
            u0 = pp[base + 512 + lane];
            u1 = pp[base + 576 + lane];
            u2 = pp[base + 640 + lane];
            u3 = pp[base + 704 + lane];
        }

        // ---- chunk V: points [base+256, base+512)
        if (colA < KNN) {
            TEST128Q(cA, colA, fA, oA, v0, v1, base + 256);
            TEST128Q(cA, colA, fA, oA, v2, v3, base + 384);
        }
        if (colB < KNN) {
            TEST128Q(cB, colB, fB, oB, v0, v1, base + 256);
            TEST128Q(cB, colB, fB, oB, v2, v3, base + 384);
        }
        if (colA >= KNN && colB >= KNN) break;
        if (base + 768 < NPTS) {            // refill v for [base+768, base+1024)
            v0 = pp[base + 768 + lane];
            v1 = pp[base + 832 + lane];
            v2 = pp[base + 896 + lane];
            v3 = pp[base + 960 + lane];
        }
    }

    // Pad tail slots [col, 32) with the first neighbor index.
    if (colA < KNN && colA + lane < KNN) oA[colA + lane] = fA;
    if (colB < KNN && colB + lane < KNN) oB[colB + lane] = fB;
}

extern "C" void kernel_launch(void* const* d_in, const int* in_sizes, int n_in,
                              void* d_out, int out_size, void* d_ws, size_t ws_size,
                              hipStream_t stream) {
    const float* pos       = (const float*)d_in[0];   // (8, 8192, 3) f32
    const int*   centroids = (const int*)d_in[1];     // (8, 2048) int32
    int*         out       = (int*)d_out;             // (8, 2048, 32) int32

    float4* pack = (float4*)d_ws;                     // 1 MiB scratch

    gg_prep<<<dim3((PACK_F4 + 255) / 256), dim3(256), 0, stream>>>(pos, pack, PACK_F4);

    const int nw = NQTOT / 2;                         // 8192 waves, 4 per block
    gg_ballquery<<<dim3(nw / 4), dim3(256), 0, stream>>>(pack, centroids, out);
}

// Round 10
// 76.418 us; speedup vs baseline: 1.1241x; 1.1241x over previous
//
#include <hip/hip_runtime.h>

#define NPTS 8192
#define NQ   2048
#define NBATCH 8
#define KNN  32
#define R2   0.04f   // fp32 cast of python 0.2**2
#define NQTOT (NBATCH * NQ)
#define PACK_F4 (NBATCH * NPTS)

// Pack pos (AoS, 12B stride) into float4(x,y,z,|p|^2). Norm with explicit
// round-to-nearest ops, no FMA contraction, reference order: (x*x+y*y)+z*z.
__global__ __launch_bounds__(256)
void gg_prep(const float* __restrict__ pos, float4* __restrict__ pack, int total) {
    int i = blockIdx.x * blockDim.x + threadIdx.x;
    if (i >= total) return;
    float x = pos[i * 3 + 0];
    float y = pos[i * 3 + 1];
    float z = pos[i * 3 + 2];
    float n = __fadd_rn(__fadd_rn(__fmul_rn(x, x), __fmul_rn(y, y)), __fmul_rn(z, z));
    pack[i] = make_float4(x, y, z, n);
}

// Lean 64-point test for one query. No first-hit tracking (pad value = slot 0,
// read back in the epilogue — valid because the centroid's own distance is
// exactly 0 in this op order, so col >= 1 always). Hit compaction goes to an
// LDS slot row via ONE unconditional ds_write with a clamped address:
// overflow/non-keep lanes write to a per-lane dump slot (distinct addresses,
// conflict-free). Distance matches reference op order exactly:
//   s = (cn + pn) - 2*((cx*px + cy*py) + cz*pz)
#define TEST64Q(C, COL, SQ, PV, SUBI)                                              \
    {                                                                              \
        float dot = __fadd_rn(__fadd_rn(__fmul_rn((C).x, (PV).x),                  \
                                        __fmul_rn((C).y, (PV).y)),                 \
                              __fmul_rn((C).z, (PV).z));                           \
        float s   = __fsub_rn(__fadd_rn((C).w, (PV).w), __fmul_rn(2.0f, dot));     \
        bool keep = !(s > R2);                                                     \
        unsigned long long m = __ballot(keep);                                     \
        if (m) {                                                                   \
            int pf = (int)__builtin_amdgcn_mbcnt_hi((unsigned)(m >> 32),           \
                         __builtin_amdgcn_mbcnt_lo((unsigned)m, 0u));              \
            int slot = (COL) + pf;                                                 \
            int a = (keep && slot < KNN) ? slot : (KNN + 2 + lane);                \
            (SQ)[a] = (SUBI) + lane;                                               \
            (COL) += (int)__popcll(m);                                             \
        }                                                                          \
    }

// One wave per TWO adjacent queries (same batch). 256 pts/iteration, loads
// issued one iteration ahead (R4-proven skeleton); per-query wave-uniform
// guards at 64-pt granularity; early exit when both queries have 32 hits.
// 4 waves/block, 2048 blocks = 8192 waves (8/SIMD). No atomics.
__global__ __launch_bounds__(256)
void gg_ballquery(const float4* __restrict__ pack,
                  const int* __restrict__ centroids,
                  int* __restrict__ out) {
    const int wid  = threadIdx.x >> 6;
    const int lane = threadIdx.x & 63;
    const int w    = blockIdx.x * 4 + wid;          // wave id: 0 .. 8191
    const int q0   = w * 2;                         // two consecutive queries
    const int b    = q0 >> 11;                      // batch

    // Per-wave, per-query slot rows: [0,32) results, [34,98) per-lane dump.
    __shared__ int slds[4][2][128];
    int* __restrict__ sqA = &slds[wid][0][0];
    int* __restrict__ sqB = &slds[wid][1][0];

    const float4* __restrict__ pp = pack + b * NPTS;

    const float4 cA = pp[centroids[q0]];
    const float4 cB = pp[centroids[q0 + 1]];

    int* __restrict__ oA = out + q0 * KNN;
    int* __restrict__ oB = oA + KNN;

    int colA = 0, colB = 0;

    // Prefetch iteration 0 (points [0, 256))
    float4 r0 = pp[lane];
    float4 r1 = pp[lane + 64];
    float4 r2 = pp[lane + 128];
    float4 r3 = pp[lane + 192];

    #pragma unroll 1
    for (int base = 0; base < NPTS; base += 256) {
        float4 p0 = r0, p1 = r1, p2 = r2, p3 = r3;
        if (base + 256 < NPTS) {                    // prefetch next 256 points
            r0 = pp[base + 256 + lane];
            r1 = pp[base + 320 + lane];
            r2 = pp[base + 384 + lane];
            r3 = pp[base + 448 + lane];
        }

        if (colA < KNN) {
            TEST64Q(cA, colA, sqA, p0, base);
            TEST64Q(cA, colA, sqA, p1, base + 64);
            TEST64Q(cA, colA, sqA, p2, base + 128);
            TEST64Q(cA, colA, sqA, p3, base + 192);
        }
        if (colB < KNN) {
            TEST64Q(cB, colB, sqB, p0, base);
            TEST64Q(cB, colB, sqB, p1, base + 64);
            TEST64Q(cB, colB, sqB, p2, base + 128);
            TEST64Q(cB, colB, sqB, p3, base + 192);
        }
        if (colA >= KNN && colB >= KNN) break;      // wave-uniform early exit
    }

    // Epilogue: slots [col,32) pad with slot 0 (the first in-radius index).
    // Same wave wrote the LDS — lockstep, no barrier needed.
    if (lane < KNN) {
        oA[lane] = sqA[(lane < colA) ? lane : 0];
        oB[lane] = sqB[(lane < colB) ? lane : 0];
    }
}

extern "C" void kernel_launch(void* const* d_in, const int* in_sizes, int n_in,
                              void* d_out, int out_size, void* d_ws, size_t ws_size,
                              hipStream_t stream) {
    const float* pos       = (const float*)d_in[0];   // (8, 8192, 3) f32
    const int*   centroids = (const int*)d_in[1];     // (8, 2048) int32
    int*         out       = (int*)d_out;             // (8, 2048, 32) int32

    float4* pack = (float4*)d_ws;                     // 1 MiB scratch

    gg_prep<<<dim3((PACK_F4 + 255) / 256), dim3(256), 0, stream>>>(pos, pack, PACK_F4);

    const int nw = NQTOT / 2;                         // 8192 waves, 4 per block
    gg_ballquery<<<dim3(nw / 4), dim3(256), 0, stream>>>(pack, centroids, out);
}